// Round 1
// baseline (679.917 us; speedup 1.0000x reference)
//
#include <hip/hip_runtime.h>

#define C_DIM   128
#define O_MAX   10
#define BN_EPS  1e-5f
#define SLOPE   0.2f

// ---------------------------------------------------------------------------
// Stage 1 (one block per batch element, 256 threads):
//   cov[o,16,16]  (grid_sample coverage weights)
//   A[o,oc,k] = sum_c labels[o,c] * w1[oc,c,k]        (rank-10 factorization)
//   h1 = lrelu(conv1) computed as sum_o A[o] (x) cov[o]
//   h2pre = conv2(h1)  -> global ws, + atomic BN2 channel sums
// ---------------------------------------------------------------------------
__global__ __launch_bounds__(256) void stage1(
    const float* __restrict__ labels,   // (B,10,128)
    const float* __restrict__ theta,    // (B,10,2,3)
    const float* __restrict__ w1,       // (64,128,3,3)
    const float* __restrict__ w2,       // (32,64,3,3)
    const int*   __restrict__ maxobj_p,
    float* __restrict__ h2pre,          // (B,32,4,4)
    float* __restrict__ bn2s, float* __restrict__ bn2s2)
{
    const int b   = blockIdx.x;
    const int tid = threadIdx.x;
    const int nobj = min(maxobj_p[0], O_MAX);

    __shared__ float s_theta[O_MAX * 6];
    __shared__ float s_labels[O_MAX * C_DIM];
    __shared__ float s_cov[O_MAX * 16 * 17];      // pitch 17 vs bank conflicts
    __shared__ float s_A[O_MAX * 576];            // 10 x (64 oc x 9 taps)
    __shared__ float s_h1[64 * 64];               // 64 ch x 8x8
    __shared__ float s_csum[32], s_csum2[32];

    if (tid < 60) s_theta[tid] = theta[b * 60 + tid];
    for (int i = tid; i < O_MAX * C_DIM; i += 256)
        s_labels[i] = labels[b * O_MAX * C_DIM + i];
    if (tid < 32) { s_csum[tid] = 0.f; s_csum2[tid] = 0.f; }
    __syncthreads();

    // ---- coverage: one pixel per thread, loop over objects ----
    {
        const int p = tid;                // 0..255
        const int y = p >> 4, x = p & 15;
        const float X = (2.f * x + 1.f) / 16.f - 1.f;
        const float Y = (2.f * y + 1.f) / 16.f - 1.f;
        for (int o = 0; o < nobj; ++o) {
            const float* t = &s_theta[o * 6];
            const float gx = t[0] * X + t[1] * Y + t[2];
            const float gy = t[3] * X + t[4] * Y + t[5];
            float ix = (gx + 1.f) * 8.f - 0.5f;
            float x0 = floorf(ix); float fx = ix - x0;
            float inx0 = (x0 >= 0.f  && x0 <= 15.f) ? 1.f : 0.f;
            float inx1 = (x0 >= -1.f && x0 <= 14.f) ? 1.f : 0.f;
            float cx = (1.f - fx) * inx0 + fx * inx1;
            float iy = (gy + 1.f) * 8.f - 0.5f;
            float y0 = floorf(iy); float fy = iy - y0;
            float iny0 = (y0 >= 0.f  && y0 <= 15.f) ? 1.f : 0.f;
            float iny1 = (y0 >= -1.f && y0 <= 14.f) ? 1.f : 0.f;
            float cy = (1.f - fy) * iny0 + fy * iny1;
            s_cov[o * 272 + y * 17 + x] = cx * cy;
        }
    }
    __syncthreads();

    // ---- A[o][oc*9+k] = sum_c labels[o][c] * w1[oc][c][k] ----
    // thread owns an (oc,k) pair; c-loop reads w1 once, 10 FMAs per load;
    // s_labels read is wave-uniform (broadcast, conflict-free).
    for (int pair = tid; pair < 576; pair += 256) {
        const int oc = pair / 9, k = pair - oc * 9;
        float acc[O_MAX];
        #pragma unroll
        for (int o = 0; o < O_MAX; ++o) acc[o] = 0.f;
        const float* wp = w1 + oc * (C_DIM * 9) + k;
        for (int c = 0; c < C_DIM; ++c) {
            const float wv = wp[c * 9];
            #pragma unroll
            for (int o = 0; o < O_MAX; ++o)
                acc[o] += s_labels[o * C_DIM + c] * wv;
        }
        for (int o = 0; o < nobj; ++o) s_A[o * 576 + pair] = acc[o];
    }
    __syncthreads();

    // ---- conv1 (stride2 pad1, 16x16 -> 8x8) via A (x) cov, + lrelu ----
    for (int i = 0; i < 16; ++i) {
        const int idx = tid + i * 256;          // 0..4095
        const int oc = idx >> 6;                // wave-uniform -> s_A broadcast
        const int p = idx & 63;
        const int y = p >> 3, x = p & 7;
        float acc = 0.f;
        for (int o = 0; o < nobj; ++o) {
            const float* Ap = &s_A[o * 576 + oc * 9];
            const float* cp = &s_cov[o * 272];
            #pragma unroll
            for (int ky = 0; ky < 3; ++ky) {
                const int iy = 2 * y - 1 + ky;
                if (iy < 0 || iy > 15) continue;
                #pragma unroll
                for (int kx = 0; kx < 3; ++kx) {
                    const int ixp = 2 * x - 1 + kx;
                    if (ixp < 0 || ixp > 15) continue;
                    acc += Ap[ky * 3 + kx] * cp[iy * 17 + ixp];
                }
            }
        }
        s_h1[oc * 64 + p] = (acc >= 0.f) ? acc : SLOPE * acc;
    }
    __syncthreads();

    // ---- conv2 (8x8 -> 4x4, 64 -> 32 ch), pre-BN out + channel sums ----
    for (int i = 0; i < 2; ++i) {
        const int idx = tid + i * 256;          // 0..511
        const int oc = idx >> 4;                // 0..31
        const int p = idx & 15;
        const int y = p >> 2, x = p & 3;
        float acc = 0.f;
        const float* wp = w2 + oc * (64 * 9);
        for (int c = 0; c < 64; ++c) {
            const float* hp = &s_h1[c * 64];
            #pragma unroll
            for (int ky = 0; ky < 3; ++ky) {
                const int iy = 2 * y - 1 + ky;
                if (iy < 0 || iy > 7) continue;
                #pragma unroll
                for (int kx = 0; kx < 3; ++kx) {
                    const int ixp = 2 * x - 1 + kx;
                    if (ixp < 0 || ixp > 7) continue;
                    acc += wp[c * 9 + ky * 3 + kx] * hp[iy * 8 + ixp];
                }
            }
        }
        h2pre[(size_t)b * 512 + idx] = acc;
        atomicAdd(&s_csum[oc], acc);
        atomicAdd(&s_csum2[oc], acc * acc);
    }
    __syncthreads();
    if (tid < 32) {
        atomicAdd(&bn2s[tid],  s_csum[tid]);
        atomicAdd(&bn2s2[tid], s_csum2[tid]);
    }
}

// ---------------------------------------------------------------------------
// Stage 2 (one block per batch element, 64 threads):
//   BN2 (from global sums) + lrelu, conv3 (4x4 -> 2x2, 32 -> 16 ch),
//   h3pre -> ws, + atomic BN3 channel sums
// ---------------------------------------------------------------------------
__global__ __launch_bounds__(64) void stage2(
    const float* __restrict__ h2pre,
    const float* __restrict__ gamma2, const float* __restrict__ beta2,
    const float* __restrict__ w3,     // (16,32,3,3)
    const float* __restrict__ bn2s, const float* __restrict__ bn2s2,
    float* __restrict__ h3pre,        // (B,16,2,2)
    float* __restrict__ bn3s, float* __restrict__ bn3s2, int B)
{
    const int b   = blockIdx.x;
    const int tid = threadIdx.x;
    __shared__ float s_scale[32], s_shift[32];
    __shared__ float s_h2a[32 * 16];
    __shared__ float s_c3[16], s_c32[16];

    if (tid < 32) {
        const float n = (float)B * 16.f;
        const float mean = bn2s[tid] / n;
        const float var  = bn2s2[tid] / n - mean * mean;
        const float sc   = gamma2[tid] * rsqrtf(var + BN_EPS);
        s_scale[tid] = sc;
        s_shift[tid] = beta2[tid] - mean * sc;
    }
    if (tid < 16) { s_c3[tid] = 0.f; s_c32[tid] = 0.f; }
    __syncthreads();

    for (int i = tid; i < 512; i += 64) {
        const int c = i >> 4;
        const float v = h2pre[(size_t)b * 512 + i] * s_scale[c] + s_shift[c];
        s_h2a[i] = (v >= 0.f) ? v : SLOPE * v;
    }
    __syncthreads();

    const int oc = tid >> 2;            // 0..15
    const int p  = tid & 3;
    const int y = p >> 1, x = p & 1;
    float acc = 0.f;
    const float* wp = w3 + oc * (32 * 9);
    for (int c = 0; c < 32; ++c) {
        #pragma unroll
        for (int ky = 0; ky < 3; ++ky) {
            const int iy = 2 * y - 1 + ky;
            if (iy < 0 || iy > 3) continue;
            #pragma unroll
            for (int kx = 0; kx < 3; ++kx) {
                const int ixp = 2 * x - 1 + kx;
                if (ixp < 0 || ixp > 3) continue;
                acc += wp[c * 9 + ky * 3 + kx] * s_h2a[c * 16 + iy * 4 + ixp];
            }
        }
    }
    h3pre[(size_t)b * 64 + tid] = acc;
    atomicAdd(&s_c3[oc],  acc);
    atomicAdd(&s_c32[oc], acc * acc);
    __syncthreads();
    if (tid < 16) {
        atomicAdd(&bn3s[tid],  s_c3[tid]);
        atomicAdd(&bn3s2[tid], s_c32[tid]);
    }
}

// ---------------------------------------------------------------------------
// Stage 3: BN3 + lrelu, elementwise -> out (B, 64) (reshape of (B,16,2,2))
// ---------------------------------------------------------------------------
__global__ __launch_bounds__(256) void stage3(
    const float* __restrict__ h3pre,
    const float* __restrict__ gamma3, const float* __restrict__ beta3,
    const float* __restrict__ bn3s, const float* __restrict__ bn3s2,
    float* __restrict__ out, int total, int B)
{
    __shared__ float s_scale[16], s_shift[16];
    if (threadIdx.x < 16) {
        const int c = threadIdx.x;
        const float n = (float)B * 4.f;
        const float mean = bn3s[c] / n;
        const float var  = bn3s2[c] / n - mean * mean;
        const float sc   = gamma3[c] * rsqrtf(var + BN_EPS);
        s_scale[c] = sc;
        s_shift[c] = beta3[c] - mean * sc;
    }
    __syncthreads();
    const int idx = blockIdx.x * 256 + threadIdx.x;
    if (idx < total) {
        const int c = (idx & 63) >> 2;
        const float v = h3pre[idx] * s_scale[c] + s_shift[c];
        out[idx] = (v >= 0.f) ? v : SLOPE * v;
    }
}

extern "C" void kernel_launch(void* const* d_in, const int* in_sizes, int n_in,
                              void* d_out, int out_size, void* d_ws, size_t ws_size,
                              hipStream_t stream)
{
    const float* labels = (const float*)d_in[0];
    const float* theta  = (const float*)d_in[1];
    const float* w1     = (const float*)d_in[2];
    const float* w2     = (const float*)d_in[3];
    const float* gamma2 = (const float*)d_in[4];
    const float* beta2  = (const float*)d_in[5];
    const float* w3     = (const float*)d_in[6];
    const float* gamma3 = (const float*)d_in[7];
    const float* beta3  = (const float*)d_in[8];
    const int*   maxobj = (const int*)d_in[9];

    const int B = in_sizes[0] / (O_MAX * C_DIM);   // 2048

    float* h2pre = (float*)d_ws;                    // B*512
    float* h3pre = h2pre + (size_t)B * 512;         // B*64
    float* sums  = h3pre + (size_t)B * 64;          // 96 floats
    float* bn2s  = sums;
    float* bn2s2 = sums + 32;
    float* bn3s  = sums + 64;
    float* bn3s2 = sums + 80;

    hipMemsetAsync(sums, 0, 96 * sizeof(float), stream);

    stage1<<<B, 256, 0, stream>>>(labels, theta, w1, w2, maxobj, h2pre, bn2s, bn2s2);
    stage2<<<B, 64, 0, stream>>>(h2pre, gamma2, beta2, w3, bn2s, bn2s2,
                                 h3pre, bn3s, bn3s2, B);
    const int total = B * 64;
    stage3<<<(total + 255) / 256, 256, 0, stream>>>(h3pre, gamma3, beta3,
                                                    bn3s, bn3s2, (float*)d_out,
                                                    total, B);
}

// Round 2
// 267.412 us; speedup vs baseline: 2.5426x; 2.5426x over previous
//
#include <hip/hip_runtime.h>

#define C_DIM   128
#define O_MAX   10
#define BN_EPS  1e-5f
#define SLOPE   0.2f

// ---------------------------------------------------------------------------
// prep: w1 (64,128,3,3) -> w1t[c=128][ock=576], ock = oc*9+kk
// ---------------------------------------------------------------------------
__global__ __launch_bounds__(256) void prep(const float* __restrict__ w1,
                                            float* __restrict__ w1t) {
    int i = blockIdx.x * 256 + threadIdx.x;
    if (i < 73728) {
        int c = i / 576, ock = i % 576;
        int oc = ock / 9, kk = ock % 9;
        w1t[i] = w1[oc * 1152 + c * 9 + kk];
    }
}

// ---------------------------------------------------------------------------
// agemm: Afull[m=(b,o)][n=(oc,kk)] = sum_c labels[m][c] * w1t[c][n]
// M=20480, N=576, K=128.  Block tile 128x64, K-tile 64, thread tile 8x4.
// ---------------------------------------------------------------------------
__global__ __launch_bounds__(256) void agemm(const float* __restrict__ L,
                                             const float* __restrict__ Bw,
                                             float* __restrict__ Cout) {
    const int bm = blockIdx.x;            // 0..159
    const int bn = blockIdx.y;            // 0..8
    const int t  = threadIdx.x;
    __shared__ float sA[64 * 132];        // [k][m], stride 132 (pad vs write conflicts)
    __shared__ float sB[64 * 64];         // [k][n]

    const int ty = t >> 4;                // 0..15 -> m0 = ty*8
    const int tx = t & 15;                // 0..15 -> n0 = tx*4
    float acc[8][4];
    #pragma unroll
    for (int i = 0; i < 8; ++i)
        #pragma unroll
        for (int j = 0; j < 4; ++j) acc[i][j] = 0.f;

    for (int ko = 0; ko < 128; ko += 64) {
        // stage A tile (128 m x 64 k), transposed into [k][m]
        #pragma unroll
        for (int j = 0; j < 8; ++j) {
            int q = t + j * 256;          // 0..2047
            int m = q >> 4, kq = q & 15;
            float4 v = *(const float4*)&L[(size_t)(bm * 128 + m) * 128 + ko + kq * 4];
            sA[(kq * 4 + 0) * 132 + m] = v.x;
            sA[(kq * 4 + 1) * 132 + m] = v.y;
            sA[(kq * 4 + 2) * 132 + m] = v.z;
            sA[(kq * 4 + 3) * 132 + m] = v.w;
        }
        // stage B tile (64 k x 64 n)
        #pragma unroll
        for (int j = 0; j < 4; ++j) {
            int q = t + j * 256;          // 0..1023
            int k = q >> 4, nq = q & 15;
            float4 v = *(const float4*)&Bw[(size_t)(ko + k) * 576 + bn * 64 + nq * 4];
            *(float4*)&sB[k * 64 + nq * 4] = v;
        }
        __syncthreads();
        #pragma unroll 4
        for (int k = 0; k < 64; ++k) {
            float4 a0 = *(float4*)&sA[k * 132 + ty * 8];
            float4 a1 = *(float4*)&sA[k * 132 + ty * 8 + 4];
            float4 b0 = *(float4*)&sB[k * 64 + tx * 4];
            float a[8] = {a0.x, a0.y, a0.z, a0.w, a1.x, a1.y, a1.z, a1.w};
            float b[4] = {b0.x, b0.y, b0.z, b0.w};
            #pragma unroll
            for (int i = 0; i < 8; ++i)
                #pragma unroll
                for (int j = 0; j < 4; ++j) acc[i][j] += a[i] * b[j];
        }
        __syncthreads();
    }
    #pragma unroll
    for (int i = 0; i < 8; ++i) {
        float4 v = make_float4(acc[i][0], acc[i][1], acc[i][2], acc[i][3]);
        *(float4*)&Cout[(size_t)(bm * 128 + ty * 8 + i) * 576 + bn * 64 + tx * 4] = v;
    }
}

// ---------------------------------------------------------------------------
// stage1: per-b block.  cov -> covp(im2col) ; load A rows ; conv1 as GEMM
// (64oc x 64px x 90) ; im2col(h1) ; conv2 as GEMM (32oc x 16px x 576)
// ---------------------------------------------------------------------------
#define COV   0        /* 10 x 18 x 18 = 3240   (o-stride 324) */
#define COVP  3240     /* [k=90][p=64] = 5760 */
#define AT    9000     /* [k=90][oc=64] = 5760 */
#define H2COL 0        /* [p=16][ck stride 580] = 9280, overlays COV..AT */
#define H1    14760    /* [oc=64][p=64] = 4096 */
#define THETA 18856    /* 60 */
#define CSUM  18916    /* 32 */
#define CSUM2 18948    /* 32 */
#define SMEMF 18980

__global__ __launch_bounds__(256) void stage1(
    const float* __restrict__ theta,    // (B,10,2,3)
    const float* __restrict__ Afull,    // (B*10, 576)
    const float* __restrict__ w2,       // (32,64,3,3) = (32,576)
    const int*   __restrict__ maxobj_p,
    float* __restrict__ h2pre,          // (B,32,4,4)
    float* __restrict__ bn2s, float* __restrict__ bn2s2)
{
    __shared__ float smem[SMEMF];
    const int b   = blockIdx.x;
    const int t   = threadIdx.x;
    const int nobj = min(maxobj_p[0], O_MAX);

    // phase 0: zero cov (incl. borders) + sums, load theta
    for (int i = t; i < 3240; i += 256) smem[COV + i] = 0.f;
    if (t < 64) smem[CSUM + t] = 0.f;        // covers CSUM+CSUM2
    if (t < 60) smem[THETA + t] = theta[b * 60 + t];
    __syncthreads();

    // phase 1a: coverage fill (interior of padded 18x18), o < nobj only
    for (int i = t; i < 2560; i += 256) {
        const int o = i >> 8;
        if (o >= nobj) continue;
        const int p = i & 255, y = p >> 4, x = p & 15;
        const float X = (2.f * x + 1.f) / 16.f - 1.f;
        const float Y = (2.f * y + 1.f) / 16.f - 1.f;
        const float* tt = &smem[THETA + o * 6];
        const float gx = tt[0] * X + tt[1] * Y + tt[2];
        const float gy = tt[3] * X + tt[4] * Y + tt[5];
        float ix = (gx + 1.f) * 8.f - 0.5f;
        float x0 = floorf(ix); float fx = ix - x0;
        float inx0 = (x0 >= 0.f  && x0 <= 15.f) ? 1.f : 0.f;
        float inx1 = (x0 >= -1.f && x0 <= 14.f) ? 1.f : 0.f;
        float cx = (1.f - fx) * inx0 + fx * inx1;
        float iy = (gy + 1.f) * 8.f - 0.5f;
        float y0 = floorf(iy); float fy = iy - y0;
        float iny0 = (y0 >= 0.f  && y0 <= 15.f) ? 1.f : 0.f;
        float iny1 = (y0 >= -1.f && y0 <= 14.f) ? 1.f : 0.f;
        float cy = (1.f - fy) * iny0 + fy * iny1;
        smem[COV + o * 324 + (y + 1) * 18 + (x + 1)] = cx * cy;
    }
    // phase 1b: load A rows for this b, scatter to At[(o*9+kk)][oc]
    {
        const float* src = Afull + (size_t)b * 5760;
        for (int i = t; i < 1440; i += 256) {
            float4 v = *(const float4*)&src[i * 4];
            float vv[4] = {v.x, v.y, v.z, v.w};
            #pragma unroll
            for (int e = 0; e < 4; ++e) {
                int j = i * 4 + e;
                int o = j / 576, ock = j % 576;
                int oc = ock / 9, kk = ock - 9 * oc;
                smem[AT + (o * 9 + kk) * 64 + oc] = vv[e];
            }
        }
    }
    __syncthreads();

    // phase 2: covp[k=(o,ky,kx)][p=(y,x)] from padded cov (branch-free)
    for (int i = t; i < 5760; i += 256) {
        const int k = i >> 6, p = i & 63;
        const int o = k / 9, kk = k - 9 * o;
        const int ky = kk / 3, kx = kk - 3 * ky;
        const int y = p >> 3, x = p & 7;
        smem[COVP + k * 64 + p] = smem[COV + o * 324 + (2 * y + ky) * 18 + (2 * x + kx)];
    }
    __syncthreads();

    // phase 3: conv1 GEMM  C1[oc][p] = sum_k At[k][oc] * covp[k][p], + lrelu
    {
        const int ty = t >> 4, tx = t & 15;
        const int oc0 = ty * 4, p0 = tx * 4;
        float acc[4][4];
        #pragma unroll
        for (int i = 0; i < 4; ++i)
            #pragma unroll
            for (int j = 0; j < 4; ++j) acc[i][j] = 0.f;
        #pragma unroll 3
        for (int k = 0; k < 90; ++k) {
            float4 a4 = *(float4*)&smem[AT + k * 64 + oc0];
            float4 c4 = *(float4*)&smem[COVP + k * 64 + p0];
            float a[4] = {a4.x, a4.y, a4.z, a4.w};
            float c[4] = {c4.x, c4.y, c4.z, c4.w};
            #pragma unroll
            for (int i = 0; i < 4; ++i)
                #pragma unroll
                for (int j = 0; j < 4; ++j) acc[i][j] += a[i] * c[j];
        }
        __syncthreads();   // all reads of COVP/AT done before H1/H2COL writes
        #pragma unroll
        for (int i = 0; i < 4; ++i) {
            float4 v;
            v.x = acc[i][0] >= 0.f ? acc[i][0] : SLOPE * acc[i][0];
            v.y = acc[i][1] >= 0.f ? acc[i][1] : SLOPE * acc[i][1];
            v.z = acc[i][2] >= 0.f ? acc[i][2] : SLOPE * acc[i][2];
            v.w = acc[i][3] >= 0.f ? acc[i][3] : SLOPE * acc[i][3];
            *(float4*)&smem[H1 + (oc0 + i) * 64 + p0] = v;
        }
    }
    __syncthreads();

    // phase 4: im2col of h1 -> H2COL[p=16][ck=576] (stride 580)
    for (int i = t; i < 9216; i += 256) {
        const int p = i & 15, ck = i >> 4;
        const int c = ck / 9, kk = ck - 9 * c;
        const int ky = kk / 3, kx = kk - 3 * ky;
        const int y = p >> 2, x = p & 3;
        const int iy = 2 * y - 1 + ky, ix = 2 * x - 1 + kx;
        float v = 0.f;
        if ((unsigned)iy < 8u && (unsigned)ix < 8u)
            v = smem[H1 + c * 64 + iy * 8 + ix];
        smem[H2COL + p * 580 + ck] = v;
    }
    __syncthreads();

    // phase 5: conv2 GEMM  C2[oc][p] = sum_ck w2[oc][ck] * H2COL[p][ck]
    {
        const int p = t & 15, og = t >> 4;          // og 0..15 -> oc {og, og+16}
        const float* w2a = w2 + og * 576;
        const float* w2b = w2 + (og + 16) * 576;
        float acca = 0.f, accb = 0.f;
        #pragma unroll 4
        for (int kq = 0; kq < 144; ++kq) {
            float4 h4 = *(float4*)&smem[H2COL + p * 580 + kq * 4];
            float4 wa = *(const float4*)(w2a + kq * 4);
            float4 wb = *(const float4*)(w2b + kq * 4);
            acca += h4.x * wa.x + h4.y * wa.y + h4.z * wa.z + h4.w * wa.w;
            accb += h4.x * wb.x + h4.y * wb.y + h4.z * wb.z + h4.w * wb.w;
        }
        h2pre[(size_t)b * 512 + og * 16 + p]        = acca;
        h2pre[(size_t)b * 512 + (og + 16) * 16 + p] = accb;
        atomicAdd(&smem[CSUM + og],        acca);
        atomicAdd(&smem[CSUM2 + og],       acca * acca);
        atomicAdd(&smem[CSUM + og + 16],   accb);
        atomicAdd(&smem[CSUM2 + og + 16],  accb * accb);
    }
    __syncthreads();
    if (t < 32) {
        atomicAdd(&bn2s[t],  smem[CSUM + t]);
        atomicAdd(&bn2s2[t], smem[CSUM2 + t]);
    }
}

// ---------------------------------------------------------------------------
// stage2: 4 batch elements per block (256 threads). BN2+lrelu, conv3, BN3 sums
// ---------------------------------------------------------------------------
__global__ __launch_bounds__(256) void stage2(
    const float* __restrict__ h2pre,
    const float* __restrict__ gamma2, const float* __restrict__ beta2,
    const float* __restrict__ w3,     // (16,32,3,3) = (16,288)
    const float* __restrict__ bn2s, const float* __restrict__ bn2s2,
    float* __restrict__ h3pre,        // (B,16,2,2)
    float* __restrict__ bn3s, float* __restrict__ bn3s2, int B)
{
    const int b0  = blockIdx.x * 4;
    const int t   = threadIdx.x;
    __shared__ float s_scale[32], s_shift[32];
    __shared__ float s_pad[4 * 32 * 36];          // per-b padded 6x6 per channel
    __shared__ float s_c3[16], s_c32[16];

    if (t < 32) {
        const float n = (float)B * 16.f;
        const float mean = bn2s[t] / n;
        const float var  = bn2s2[t] / n - mean * mean;
        const float sc   = gamma2[t] * rsqrtf(var + BN_EPS);
        s_scale[t] = sc;
        s_shift[t] = beta2[t] - mean * sc;
    }
    if (t < 16) { s_c3[t] = 0.f; s_c32[t] = 0.f; }
    for (int i = t; i < 4 * 32 * 36; i += 256) s_pad[i] = 0.f;
    __syncthreads();

    for (int i = t; i < 2048; i += 256) {
        const int lb = i >> 9, r = i & 511;
        const int c = r >> 4, p = r & 15, y = p >> 2, x = p & 3;
        const float v = h2pre[(size_t)b0 * 512 + i] * s_scale[c] + s_shift[c];
        const float a = (v >= 0.f) ? v : SLOPE * v;
        s_pad[lb * 1152 + c * 36 + (y + 1) * 6 + (x + 1)] = a;
    }
    __syncthreads();

    {
        const int lb = t >> 6, r = t & 63;
        const int oc = r >> 2, p = r & 3, y = p >> 1, x = p & 1;
        float acc = 0.f;
        const float* wp = w3 + oc * 288;
        const float* hp = &s_pad[lb * 1152];
        for (int c = 0; c < 32; ++c) {
            const float* hc = hp + c * 36;
            #pragma unroll
            for (int ky = 0; ky < 3; ++ky)
                #pragma unroll
                for (int kx = 0; kx < 3; ++kx)
                    acc += wp[c * 9 + ky * 3 + kx] * hc[(2 * y + ky) * 6 + (2 * x + kx)];
        }
        h3pre[(size_t)b0 * 64 + t] = acc;
        atomicAdd(&s_c3[oc],  acc);
        atomicAdd(&s_c32[oc], acc * acc);
    }
    __syncthreads();
    if (t < 16) {
        atomicAdd(&bn3s[t],  s_c3[t]);
        atomicAdd(&bn3s2[t], s_c32[t]);
    }
}

// ---------------------------------------------------------------------------
// stage3: BN3 + lrelu -> out (B, 64)
// ---------------------------------------------------------------------------
__global__ __launch_bounds__(256) void stage3(
    const float* __restrict__ h3pre,
    const float* __restrict__ gamma3, const float* __restrict__ beta3,
    const float* __restrict__ bn3s, const float* __restrict__ bn3s2,
    float* __restrict__ out, int total, int B)
{
    __shared__ float s_scale[16], s_shift[16];
    if (threadIdx.x < 16) {
        const int c = threadIdx.x;
        const float n = (float)B * 4.f;
        const float mean = bn3s[c] / n;
        const float var  = bn3s2[c] / n - mean * mean;
        const float sc   = gamma3[c] * rsqrtf(var + BN_EPS);
        s_scale[c] = sc;
        s_shift[c] = beta3[c] - mean * sc;
    }
    __syncthreads();
    const int idx = blockIdx.x * 256 + threadIdx.x;
    if (idx < total) {
        const int c = (idx & 63) >> 2;
        const float v = h3pre[idx] * s_scale[c] + s_shift[c];
        out[idx] = (v >= 0.f) ? v : SLOPE * v;
    }
}

extern "C" void kernel_launch(void* const* d_in, const int* in_sizes, int n_in,
                              void* d_out, int out_size, void* d_ws, size_t ws_size,
                              hipStream_t stream)
{
    const float* labels = (const float*)d_in[0];
    const float* theta  = (const float*)d_in[1];
    const float* w1     = (const float*)d_in[2];
    const float* w2     = (const float*)d_in[3];
    const float* gamma2 = (const float*)d_in[4];
    const float* beta2  = (const float*)d_in[5];
    const float* w3     = (const float*)d_in[6];
    const float* gamma3 = (const float*)d_in[7];
    const float* beta3  = (const float*)d_in[8];
    const int*   maxobj = (const int*)d_in[9];

    const int B = in_sizes[0] / (O_MAX * C_DIM);   // 2048
    const int M = B * O_MAX;                       // 20480

    float* ws    = (float*)d_ws;
    float* w1t   = ws;                              // 73728
    float* Afull = w1t + 73728;                     // M*576
    float* h2pre = Afull + (size_t)M * 576;         // B*512
    float* h3pre = h2pre + (size_t)B * 512;         // B*64
    float* sums  = h3pre + (size_t)B * 64;          // 96
    float* bn2s  = sums;
    float* bn2s2 = sums + 32;
    float* bn3s  = sums + 64;
    float* bn3s2 = sums + 80;

    hipMemsetAsync(sums, 0, 96 * sizeof(float), stream);

    prep<<<288, 256, 0, stream>>>(w1, w1t);
    dim3 ggrid(M / 128, 9);
    agemm<<<ggrid, 256, 0, stream>>>(labels, w1t, Afull);
    stage1<<<B, 256, 0, stream>>>(theta, Afull, w2, maxobj, h2pre, bn2s, bn2s2);
    stage2<<<B / 4, 256, 0, stream>>>(h2pre, gamma2, beta2, w3, bn2s, bn2s2,
                                      h3pre, bn3s, bn3s2, B);
    const int total = B * 64;
    stage3<<<(total + 255) / 256, 256, 0, stream>>>(h3pre, gamma3, beta3,
                                                    bn3s, bn3s2, (float*)d_out,
                                                    total, B);
}

// Round 3
// 238.914 us; speedup vs baseline: 2.8459x; 1.1193x over previous
//
#include <hip/hip_runtime.h>

#define C_DIM   128
#define O_MAX   10
#define BN_EPS  1e-5f
#define SLOPE   0.2f

typedef short s8v  __attribute__((ext_vector_type(8)));   // 8 bf16 (4 VGPRs)
typedef float f4v  __attribute__((ext_vector_type(4)));   // MFMA accumulator
#define MFMA(a,b,c) __builtin_amdgcn_mfma_f32_16x16x32_bf16(a,b,c,0,0,0)

__device__ inline unsigned short f2bf(float f) {          // RNE fp32->bf16
    unsigned u = __float_as_uint(f);
    unsigned r = u + 0x7FFFu + ((u >> 16) & 1u);
    return (unsigned short)(r >> 16);
}

// ---------------------------------------------------------------------------
// prep: labels->bf16 ; w1n[n=(kk,oc)][c=128] bf16 ; w2b[oc][tap*64+c] bf16
// (pad to 584) ; zero BN sums.
// ---------------------------------------------------------------------------
#define N_LAB4 655360      /* 2621440/4 float4 groups */
#define N_W1N  73728
#define N_W2B  18688       /* 32*584 */
__global__ __launch_bounds__(256) void prep(
    const float* __restrict__ labels, const float* __restrict__ w1,
    const float* __restrict__ w2,
    short* __restrict__ labbf, short* __restrict__ w1n, short* __restrict__ w2b,
    float* __restrict__ sums)
{
    int i = blockIdx.x * 256 + threadIdx.x;
    if (i < N_LAB4) {
        float4 v = *(const float4*)&labels[(size_t)i * 4];
        unsigned lo = f2bf(v.x) | ((unsigned)f2bf(v.y) << 16);
        unsigned hi = f2bf(v.z) | ((unsigned)f2bf(v.w) << 16);
        *(uint2*)&labbf[(size_t)i * 4] = make_uint2(lo, hi);
        return;
    }
    i -= N_LAB4;
    if (i < N_W1N) {                       // w1n[n][c] = w1[oc][c][kk], n=kk*64+oc
        int n = i >> 7, c = i & 127;
        int kk = n >> 6, oc = n & 63;
        w1n[i] = f2bf(w1[oc * 1152 + c * 9 + kk]);
        return;
    }
    i -= N_W1N;
    if (i < N_W2B) {                       // w2b[oc][k2], k2 = tap*64+c
        int oc = i / 584, k2 = i % 584;
        int tap = k2 >> 6, c = k2 & 63;
        w2b[i] = (k2 < 576) ? f2bf(w2[oc * 576 + c * 9 + tap]) : (short)0;
        return;
    }
    i -= N_W2B;
    if (i < 96) sums[i] = 0.f;
}

// ---------------------------------------------------------------------------
// agemm (MFMA): C[m=(b,o)][n=(kk,oc)] = sum_c labbf[m][c] * w1n[n][c]
// M=20480, N=576, K=128.  Block = 4 waves, tile 64m x 64n, frags from global.
// Output scattered to Afull2[(b*64+oc)][104] bf16 with col = o*9+kk.
// ---------------------------------------------------------------------------
__global__ __launch_bounds__(256) void agemm(
    const short* __restrict__ Lb, const short* __restrict__ Wn,
    short* __restrict__ A2)
{
    const int bm = blockIdx.x, bn = blockIdx.y;
    const int t = threadIdx.x, w = t >> 6, l = t & 63;
    const int lm = l & 15, lq = l >> 4;

    const short* arow = Lb + (size_t)(bm * 64 + w * 16 + lm) * 128 + lq * 8;
    const short* brow = Wn + (size_t)(bn * 64 + lm) * 128 + lq * 8;

    f4v acc[4];
    #pragma unroll
    for (int nt = 0; nt < 4; ++nt) acc[nt] = (f4v){0.f, 0.f, 0.f, 0.f};

    #pragma unroll
    for (int ks = 0; ks < 4; ++ks) {
        s8v a = *(const s8v*)(arow + ks * 32);
        #pragma unroll
        for (int nt = 0; nt < 4; ++nt) {
            s8v b = *(const s8v*)(brow + nt * 2048 + ks * 32);
            acc[nt] = MFMA(a, b, acc[nt]);
        }
    }
    #pragma unroll
    for (int nt = 0; nt < 4; ++nt) {
        const int n = bn * 64 + nt * 16 + lm;
        const int kk = n >> 6, oc = n & 63;
        #pragma unroll
        for (int r = 0; r < 4; ++r) {
            const int m = bm * 64 + w * 16 + lq * 4 + r;
            const int b = m / 10, o = m - 10 * b;
            A2[(size_t)(b * 64 + oc) * 104 + o * 9 + kk] = (short)f2bf(acc[nt][r]);
        }
    }
}

// ---------------------------------------------------------------------------
// stage1 (per-b block, 256 thr): cov -> covpT bf16 ; AT2 copy ; conv1 MFMA ;
// lrelu -> h1T bf16 (padded 10x10, stride 66) ; im2col -> h2colT ; conv2 MFMA
// (K split across wave pairs) ; BN2 sums.
// LDS map (bytes):  COVf 0..12960 | CPT 12960..26272 | AT2 26272..39584
// overlays: H1T 0..13200 (after conv1 reads) | H2C 13216..31904 (after conv1)
// SCR 39584..41632 | THETA 41632.. | CS 41872.. | CS2 42000..42128
// ---------------------------------------------------------------------------
__global__ __launch_bounds__(256) void stage1(
    const float* __restrict__ theta,
    const short* __restrict__ A2,       // (B*64, 104) bf16
    const short* __restrict__ w2b,      // (32, 584) bf16
    const int*   __restrict__ maxobj_p,
    float* __restrict__ h2pre,          // (B,32,4,4)
    float* __restrict__ bn2s, float* __restrict__ bn2s2)
{
    __shared__ __align__(16) unsigned char smem[42128];
    float* COVf = (float*)(smem);
    short* CPT  = (short*)(smem + 12960);
    short* AT2  = (short*)(smem + 26272);
    short* H1T  = (short*)(smem);
    short* H2C  = (short*)(smem + 13216);
    float* SCR  = (float*)(smem + 39584);
    float* TH   = (float*)(smem + 41632);
    float* CS   = (float*)(smem + 41872);
    float* CS2  = (float*)(smem + 42000);

    const int b = blockIdx.x, t = threadIdx.x;
    const int w = t >> 6, l = t & 63, lm = l & 15, lq = l >> 4;
    const int nobj = min(maxobj_p[0], O_MAX);

    // phase 0: zero COV (f32) + covpT (bf16), load theta
    for (int i = t; i < 3240; i += 256) COVf[i] = 0.f;
    for (int i = t; i < 3328; i += 256) ((unsigned*)CPT)[i] = 0u;
    if (t < 60) TH[t] = theta[b * 60 + t];
    __syncthreads();

    // phase 1a: coverage (interior of padded 18x18)
    for (int i = t; i < 2560; i += 256) {
        const int o = i >> 8;
        if (o >= nobj) continue;
        const int p = i & 255, y = p >> 4, x = p & 15;
        const float X = (2.f * x + 1.f) / 16.f - 1.f;
        const float Y = (2.f * y + 1.f) / 16.f - 1.f;
        const float* tt = &TH[o * 6];
        const float gx = tt[0] * X + tt[1] * Y + tt[2];
        const float gy = tt[3] * X + tt[4] * Y + tt[5];
        float ix = (gx + 1.f) * 8.f - 0.5f;
        float x0 = floorf(ix); float fx = ix - x0;
        float inx0 = (x0 >= 0.f  && x0 <= 15.f) ? 1.f : 0.f;
        float inx1 = (x0 >= -1.f && x0 <= 14.f) ? 1.f : 0.f;
        float cx = (1.f - fx) * inx0 + fx * inx1;
        float iy = (gy + 1.f) * 8.f - 0.5f;
        float y0 = floorf(iy); float fy = iy - y0;
        float iny0 = (y0 >= 0.f  && y0 <= 15.f) ? 1.f : 0.f;
        float iny1 = (y0 >= -1.f && y0 <= 14.f) ? 1.f : 0.f;
        float cy = (1.f - fy) * iny0 + fy * iny1;
        COVf[o * 324 + (y + 1) * 18 + (x + 1)] = cx * cy;
    }
    // phase 1b: AT2 <- Afull2[b] straight b128 copy (832 uint4)
    {
        const uint4* src = (const uint4*)(A2 + (size_t)b * 6656);
        uint4* dst = (uint4*)AT2;
        for (int i = t; i < 832; i += 256) dst[i] = src[i];
    }
    __syncthreads();

    // phase 2: covpT[p][k] bf16 (k = o*9 + ky*3 + kx), zeros already cover
    // k in [90,96) and o >= nobj
    for (int i = t; i < 5760; i += 256) {
        const int k = i >> 6, p = i & 63;
        const int o = k / 9, kk = k - 9 * o;
        if (o < nobj) {
            const int ky = kk / 3, kx = kk - 3 * ky;
            const int y = p >> 3, x = p & 7;
            CPT[p * 104 + k] = (short)f2bf(COVf[o * 324 + (2 * y + ky) * 18 + (2 * x + kx)]);
        }
    }
    __syncthreads();

    // phase 3: conv1 MFMA.  wave w -> oc tile [16w,16w+16); 4 n-tiles; K=96
    f4v c1[4];
    #pragma unroll
    for (int nt = 0; nt < 4; ++nt) c1[nt] = (f4v){0.f, 0.f, 0.f, 0.f};
    {
        const short* at = AT2 + (16 * w + lm) * 104 + lq * 8;
        const short* cp = CPT + lm * 104 + lq * 8;
        #pragma unroll
        for (int ks = 0; ks < 3; ++ks) {
            s8v a = *(const s8v*)(at + ks * 32);
            #pragma unroll
            for (int nt = 0; nt < 4; ++nt) {
                s8v bb = *(const s8v*)(cp + nt * 1664 + ks * 32);
                c1[nt] = MFMA(a, bb, c1[nt]);
            }
        }
    }
    __syncthreads();   // all covpT/AT2 reads done before H1T overlay writes

    // conv1 epilogue: zero H1T border rows, write lrelu(bf16) interior
    for (int i = t; i < 1188; i += 256) {           // 36 border rows x 33 u32
        const int j = i / 33, col = i - 33 * j;
        int r;
        if (j < 10) r = j;
        else if (j < 20) r = 90 + (j - 10);
        else { int jj = j - 20; r = 10 + (jj >> 1) * 10 + ((jj & 1) ? 9 : 0); }
        ((unsigned*)H1T)[r * 33 + col] = 0u;
    }
    #pragma unroll
    for (int nt = 0; nt < 4; ++nt) {
        const int p = nt * 16 + lm, y = p >> 3, x = p & 7;
        const int pix = (y + 1) * 10 + (x + 1);
        #pragma unroll
        for (int r = 0; r < 4; ++r) {
            const int oc = 16 * w + lq * 4 + r;
            float v = c1[nt][r];
            v = (v >= 0.f) ? v : SLOPE * v;
            H1T[pix * 66 + oc] = (short)f2bf(v);
        }
    }
    __syncthreads();

    // phase 4: im2col pairs -> h2colT[p2][k2=tap*64+c] (stride 584)
    for (int i = t; i < 4608; i += 256) {
        const int p2 = i & 15, kp = i >> 4;         // kp = tap*32 + c2
        const int c2 = kp & 31, tap = kp >> 5;
        const int ky = (tap * 11) >> 5, kx = tap - 3 * ky;
        const int y2 = p2 >> 2, x2 = p2 & 3;
        const int pix = (2 * y2 + ky) * 10 + (2 * x2 + kx);
        const unsigned v = *(const unsigned*)&H1T[pix * 66 + 2 * c2];
        *(unsigned*)&H2C[p2 * 584 + tap * 64 + 2 * c2] = v;
    }
    __syncthreads();

    // phase 5: conv2 MFMA. wave: mi = w&1 (oc tile), kh = w>>1 (K half)
    {
        const int mi = w & 1, kh = w >> 1;
        f4v c2 = (f4v){0.f, 0.f, 0.f, 0.f};
        const short* wrow = w2b + (mi * 16 + lm) * 584 + kh * 288 + lq * 8;
        const short* hrow = H2C + lm * 584 + kh * 288 + lq * 8;
        #pragma unroll
        for (int ks = 0; ks < 9; ++ks) {
            s8v a  = *(const s8v*)(wrow + ks * 32);
            s8v bb = *(const s8v*)(hrow + ks * 32);
            c2 = MFMA(a, bb, c2);
        }
        if (kh == 1) *(f4v*)&SCR[(mi * 64 + l) * 4] = c2;
        __syncthreads();
        if (kh == 0) {
            f4v oth = *(const f4v*)&SCR[(mi * 64 + l) * 4];
            #pragma unroll
            for (int r = 0; r < 4; ++r) {
                const int oc = mi * 16 + lq * 4 + r;
                float v = c2[r] + oth[r];
                h2pre[(size_t)b * 512 + oc * 16 + lm] = v;
                float s1 = v, s2 = v * v;
                #pragma unroll
                for (int m = 1; m < 16; m <<= 1) {
                    s1 += __shfl_xor(s1, m, 16);
                    s2 += __shfl_xor(s2, m, 16);
                }
                if (lm == 0) { CS[oc] = s1; CS2[oc] = s2; }
            }
        }
    }
    __syncthreads();
    if (t < 32) {
        atomicAdd(&bn2s[t],  CS[t]);
        atomicAdd(&bn2s2[t], CS2[t]);
    }
}

// ---------------------------------------------------------------------------
// stage2: 4 b per block. BN2+lrelu, conv3, BN3 sums   (unchanged from R2)
// ---------------------------------------------------------------------------
__global__ __launch_bounds__(256) void stage2(
    const float* __restrict__ h2pre,
    const float* __restrict__ gamma2, const float* __restrict__ beta2,
    const float* __restrict__ w3,
    const float* __restrict__ bn2s, const float* __restrict__ bn2s2,
    float* __restrict__ h3pre,
    float* __restrict__ bn3s, float* __restrict__ bn3s2, int B)
{
    const int b0 = blockIdx.x * 4, t = threadIdx.x;
    __shared__ float s_scale[32], s_shift[32];
    __shared__ float s_pad[4 * 32 * 36];
    __shared__ float s_c3[16], s_c32[16];

    if (t < 32) {
        const float n = (float)B * 16.f;
        const float mean = bn2s[t] / n;
        const float var  = bn2s2[t] / n - mean * mean;
        const float sc   = gamma2[t] * rsqrtf(var + BN_EPS);
        s_scale[t] = sc;
        s_shift[t] = beta2[t] - mean * sc;
    }
    if (t < 16) { s_c3[t] = 0.f; s_c32[t] = 0.f; }
    for (int i = t; i < 4 * 32 * 36; i += 256) s_pad[i] = 0.f;
    __syncthreads();

    for (int i = t; i < 2048; i += 256) {
        const int lb = i >> 9, r = i & 511;
        const int c = r >> 4, p = r & 15, y = p >> 2, x = p & 3;
        const float v = h2pre[(size_t)b0 * 512 + i] * s_scale[c] + s_shift[c];
        const float a = (v >= 0.f) ? v : SLOPE * v;
        s_pad[lb * 1152 + c * 36 + (y + 1) * 6 + (x + 1)] = a;
    }
    __syncthreads();

    {
        const int lb = t >> 6, r = t & 63;
        const int oc = r >> 2, p = r & 3, y = p >> 1, x = p & 1;
        float acc = 0.f;
        const float* wp = w3 + oc * 288;
        const float* hp = &s_pad[lb * 1152];
        for (int c = 0; c < 32; ++c) {
            const float* hc = hp + c * 36;
            #pragma unroll
            for (int ky = 0; ky < 3; ++ky)
                #pragma unroll
                for (int kx = 0; kx < 3; ++kx)
                    acc += wp[c * 9 + ky * 3 + kx] * hc[(2 * y + ky) * 6 + (2 * x + kx)];
        }
        h3pre[(size_t)b0 * 64 + t] = acc;
        atomicAdd(&s_c3[oc],  acc);
        atomicAdd(&s_c32[oc], acc * acc);
    }
    __syncthreads();
    if (t < 16) {
        atomicAdd(&bn3s[t],  s_c3[t]);
        atomicAdd(&bn3s2[t], s_c32[t]);
    }
}

// ---------------------------------------------------------------------------
// stage3: BN3 + lrelu -> out
// ---------------------------------------------------------------------------
__global__ __launch_bounds__(256) void stage3(
    const float* __restrict__ h3pre,
    const float* __restrict__ gamma3, const float* __restrict__ beta3,
    const float* __restrict__ bn3s, const float* __restrict__ bn3s2,
    float* __restrict__ out, int total, int B)
{
    __shared__ float s_scale[16], s_shift[16];
    if (threadIdx.x < 16) {
        const int c = threadIdx.x;
        const float n = (float)B * 4.f;
        const float mean = bn3s[c] / n;
        const float var  = bn3s2[c] / n - mean * mean;
        const float sc   = gamma3[c] * rsqrtf(var + BN_EPS);
        s_scale[c] = sc;
        s_shift[c] = beta3[c] - mean * sc;
    }
    __syncthreads();
    const int idx = blockIdx.x * 256 + threadIdx.x;
    if (idx < total) {
        const int c = (idx & 63) >> 2;
        const float v = h3pre[idx] * s_scale[c] + s_shift[c];
        out[idx] = (v >= 0.f) ? v : SLOPE * v;
    }
}

extern "C" void kernel_launch(void* const* d_in, const int* in_sizes, int n_in,
                              void* d_out, int out_size, void* d_ws, size_t ws_size,
                              hipStream_t stream)
{
    const float* labels = (const float*)d_in[0];
    const float* theta  = (const float*)d_in[1];
    const float* w1     = (const float*)d_in[2];
    const float* w2     = (const float*)d_in[3];
    const float* gamma2 = (const float*)d_in[4];
    const float* beta2  = (const float*)d_in[5];
    const float* w3     = (const float*)d_in[6];
    const float* gamma3 = (const float*)d_in[7];
    const float* beta3  = (const float*)d_in[8];
    const int*   maxobj = (const int*)d_in[9];

    const int B = in_sizes[0] / (O_MAX * C_DIM);   // 2048
    const int M = B * O_MAX;                       // 20480

    unsigned char* ws = (unsigned char*)d_ws;
    short* labbf = (short*)ws;                                   // 2,621,440 sh
    short* w1n   = (short*)(ws + 5242880);                       // 73,728 sh
    short* w2b   = (short*)(ws + 5390336);                       // 18,688 sh
    short* A2    = (short*)(ws + 5427712);                       // B*64*104 sh
    float* h2pre = (float*)(ws + 5427712 + (size_t)B * 64 * 104 * 2);
    float* h3pre = h2pre + (size_t)B * 512;
    float* sums  = h3pre + (size_t)B * 64;
    float* bn2s  = sums;
    float* bn2s2 = sums + 32;
    float* bn3s  = sums + 64;
    float* bn3s2 = sums + 80;

    const int prep_total = N_LAB4 + N_W1N + N_W2B + 96;
    prep<<<(prep_total + 255) / 256, 256, 0, stream>>>(labels, w1, w2,
                                                       labbf, w1n, w2b, sums);
    dim3 ggrid(M / 64, 9);
    agemm<<<ggrid, 256, 0, stream>>>(labbf, w1n, A2);
    stage1<<<B, 256, 0, stream>>>(theta, A2, w2b, maxobj, h2pre, bn2s, bn2s2);
    stage2<<<B / 4, 256, 0, stream>>>(h2pre, gamma2, beta2, w3, bn2s, bn2s2,
                                      h3pre, bn3s, bn3s2, B);
    const int total = B * 64;
    stage3<<<(total + 255) / 256, 256, 0, stream>>>(h3pre, gamma3, beta3,
                                                    bn3s, bn3s2, (float*)d_out,
                                                    total, B);
}

// Round 4
// 183.043 us; speedup vs baseline: 3.7145x; 1.3052x over previous
//
#include <hip/hip_runtime.h>

#define C_DIM   128
#define O_MAX   10
#define BN_EPS  1e-5f
#define SLOPE   0.2f

typedef short s8v  __attribute__((ext_vector_type(8)));   // 8 bf16 (4 VGPRs)
typedef float f4v  __attribute__((ext_vector_type(4)));   // MFMA accumulator
#define MFMA(a,b,c) __builtin_amdgcn_mfma_f32_16x16x32_bf16(a,b,c,0,0,0)

__device__ inline unsigned short f2bf(float f) {          // RNE fp32->bf16
    unsigned u = __float_as_uint(f);
    unsigned r = u + 0x7FFFu + ((u >> 16) & 1u);
    return (unsigned short)(r >> 16);
}

// ---------------------------------------------------------------------------
// prep: w1n[n=(kk,oc)][c=128] bf16 ; w2b[oc][tap*64+c] bf16 (pad 584) ;
// zero BN sums.  (labels no longer precopied - stage1 casts in-block)
// ---------------------------------------------------------------------------
#define N_W1N  73728
#define N_W2B  18688       /* 32*584 */
__global__ __launch_bounds__(256) void prep(
    const float* __restrict__ w1, const float* __restrict__ w2,
    short* __restrict__ w1n, short* __restrict__ w2b,
    float* __restrict__ sums)
{
    int i = blockIdx.x * 256 + threadIdx.x;
    if (i < N_W1N) {                       // w1n[n][c] = w1[oc][c][kk], n=kk*64+oc
        int n = i >> 7, c = i & 127;
        int kk = n >> 6, oc = n & 63;
        w1n[i] = f2bf(w1[oc * 1152 + c * 9 + kk]);
        return;
    }
    i -= N_W1N;
    if (i < N_W2B) {                       // w2b[oc][k2], k2 = tap*64+c
        int oc = i / 584, k2 = i % 584;
        int tap = k2 >> 6, c = k2 & 63;
        w2b[i] = (k2 < 576) ? f2bf(w2[oc * 576 + c * 9 + tap]) : (short)0;
        return;
    }
    i -= N_W2B;
    if (i < 96) sums[i] = 0.f;
}

// ---------------------------------------------------------------------------
// stage1 (per-b block, 256 thr):
//   labels[b] fp32 -> LBF bf16 ; cov -> COVf ; A-GEMM MFMA (LBF x w1n-global)
//   -> scatter AT2 (LDS) ; covpT bf16 ; conv1 MFMA ; lrelu -> h1T ; im2col ;
//   conv2 MFMA (K split across wave pairs) ; BN2 sums.
// LDS (bytes): COVf 0..12960 | CPT 12960..26272 | AT2 26272..39584 |
//   LBF 39584..43680 | SCR 43680..45728 | TH 45728.. | CS 45968.. | CS2 46096
// overlays (dead after conv1): H1T 0..13200 | H2C 13216..31904
// ---------------------------------------------------------------------------
__global__ __launch_bounds__(256) void stage1(
    const float* __restrict__ labels,   // (B,10,128) fp32
    const float* __restrict__ theta,
    const short* __restrict__ w1n,      // (576,128) bf16, n=kk*64+oc
    const short* __restrict__ w2b,      // (32,584) bf16
    const int*   __restrict__ maxobj_p,
    float* __restrict__ h2pre,          // (B,32,4,4)
    float* __restrict__ bn2s, float* __restrict__ bn2s2)
{
    __shared__ __align__(16) unsigned char smem[46224];
    float* COVf = (float*)(smem);
    short* CPT  = (short*)(smem + 12960);
    short* AT2  = (short*)(smem + 26272);
    short* LBF  = (short*)(smem + 39584);
    short* H1T  = (short*)(smem);
    short* H2C  = (short*)(smem + 13216);
    float* SCR  = (float*)(smem + 43680);
    float* TH   = (float*)(smem + 45728);
    float* CS   = (float*)(smem + 45968);
    float* CS2  = (float*)(smem + 46096);

    const int b = blockIdx.x, t = threadIdx.x;
    const int w = t >> 6, l = t & 63, lm = l & 15, lq = l >> 4;
    const int nobj = min(maxobj_p[0], O_MAX);

    // ---- phase 0: zero COVf/CPT/AT2, LBF rows 0-9 from labels + 10-15 zero
    for (int i = t; i < 3240; i += 256) COVf[i] = 0.f;
    for (int i = t; i < 3328; i += 256) ((unsigned*)CPT)[i] = 0u;
    for (int i = t; i < 3328; i += 256) ((unsigned*)AT2)[i] = 0u;
    for (int i = t; i < 320; i += 256) {             // 10 rows x 128 c / 4
        float4 v = *(const float4*)&labels[(size_t)b * 1280 + i * 4];
        unsigned lo = f2bf(v.x) | ((unsigned)f2bf(v.y) << 16);
        unsigned hi = f2bf(v.z) | ((unsigned)f2bf(v.w) << 16);
        *(uint2*)&LBF[i * 4] = make_uint2(lo, hi);
    }
    for (int i = t; i < 384; i += 256) ((unsigned*)LBF)[640 + i] = 0u;
    if (t < 60) TH[t] = theta[b * 60 + t];
    __syncthreads();

    // ---- phase 1a: coverage (interior of padded 18x18) -> COVf
    for (int i = t; i < 2560; i += 256) {
        const int o = i >> 8;
        if (o >= nobj) continue;
        const int p = i & 255, y = p >> 4, x = p & 15;
        const float X = (2.f * x + 1.f) / 16.f - 1.f;
        const float Y = (2.f * y + 1.f) / 16.f - 1.f;
        const float* tt = &TH[o * 6];
        const float gx = tt[0] * X + tt[1] * Y + tt[2];
        const float gy = tt[3] * X + tt[4] * Y + tt[5];
        float ix = (gx + 1.f) * 8.f - 0.5f;
        float x0 = floorf(ix); float fx = ix - x0;
        float inx0 = (x0 >= 0.f  && x0 <= 15.f) ? 1.f : 0.f;
        float inx1 = (x0 >= -1.f && x0 <= 14.f) ? 1.f : 0.f;
        float cx = (1.f - fx) * inx0 + fx * inx1;
        float iy = (gy + 1.f) * 8.f - 0.5f;
        float y0 = floorf(iy); float fy = iy - y0;
        float iny0 = (y0 >= 0.f  && y0 <= 15.f) ? 1.f : 0.f;
        float iny1 = (y0 >= -1.f && y0 <= 14.f) ? 1.f : 0.f;
        float cy = (1.f - fy) * iny0 + fy * iny1;
        COVf[o * 324 + (y + 1) * 18 + (x + 1)] = cx * cy;
    }

    // ---- phase 1b: fused A-GEMM.  wave w owns n in [w*144, w*144+144).
    // C[m=o][n=(kk,oc)] = sum_c LBF[m][c] * w1n[n][c]; scatter bf16 -> AT2.
    {
        const int n00 = w * 144;
        s8v afr[4];
        #pragma unroll
        for (int ks = 0; ks < 4; ++ks)
            afr[ks] = *(const s8v*)&LBF[lm * 128 + lq * 8 + ks * 32];
        #pragma unroll
        for (int nt = 0; nt < 9; ++nt) {
            const int n = n00 + nt * 16 + lm;
            const short* brow = w1n + (size_t)n * 128 + lq * 8;
            f4v acc = (f4v){0.f, 0.f, 0.f, 0.f};
            #pragma unroll
            for (int ks = 0; ks < 4; ++ks) {
                s8v bb = *(const s8v*)(brow + ks * 32);
                acc = MFMA(afr[ks], bb, acc);
            }
            const int kk = n >> 6, oc = n & 63;
            #pragma unroll
            for (int r = 0; r < 4; ++r) {
                const int m = lq * 4 + r;
                if (m < 10)
                    AT2[oc * 104 + m * 9 + kk] = (short)f2bf(acc[r]);
            }
        }
    }
    __syncthreads();

    // ---- phase 2: covpT[p][k] bf16 (k = o*9+kk); zeros gate k>=90, o>=nobj
    for (int i = t; i < 5760; i += 256) {
        const int k = i >> 6, p = i & 63;
        const int o = k / 9, kk = k - 9 * o;
        if (o < nobj) {
            const int ky = kk / 3, kx = kk - 3 * ky;
            const int y = p >> 3, x = p & 7;
            CPT[p * 104 + k] = (short)f2bf(COVf[o * 324 + (2 * y + ky) * 18 + (2 * x + kx)]);
        }
    }
    __syncthreads();

    // ---- phase 3: conv1 MFMA.  wave w -> oc tile [16w,16w+16); K=96
    f4v c1[4];
    #pragma unroll
    for (int nt = 0; nt < 4; ++nt) c1[nt] = (f4v){0.f, 0.f, 0.f, 0.f};
    {
        const short* at = AT2 + (16 * w + lm) * 104 + lq * 8;
        const short* cp = CPT + lm * 104 + lq * 8;
        #pragma unroll
        for (int ks = 0; ks < 3; ++ks) {
            s8v a = *(const s8v*)(at + ks * 32);
            #pragma unroll
            for (int nt = 0; nt < 4; ++nt) {
                s8v bb = *(const s8v*)(cp + nt * 1664 + ks * 32);
                c1[nt] = MFMA(a, bb, c1[nt]);
            }
        }
    }
    __syncthreads();   // covpT/AT2 reads done before H1T overlay writes

    // conv1 epilogue: zero H1T border rows, write lrelu(bf16) interior
    for (int i = t; i < 1188; i += 256) {           // 36 border rows x 33 u32
        const int j = i / 33, col = i - 33 * j;
        int r;
        if (j < 10) r = j;
        else if (j < 20) r = 90 + (j - 10);
        else { int jj = j - 20; r = 10 + (jj >> 1) * 10 + ((jj & 1) ? 9 : 0); }
        ((unsigned*)H1T)[r * 33 + col] = 0u;
    }
    #pragma unroll
    for (int nt = 0; nt < 4; ++nt) {
        const int p = nt * 16 + lm, y = p >> 3, x = p & 7;
        const int pix = (y + 1) * 10 + (x + 1);
        #pragma unroll
        for (int r = 0; r < 4; ++r) {
            const int oc = 16 * w + lq * 4 + r;
            float v = c1[nt][r];
            v = (v >= 0.f) ? v : SLOPE * v;
            H1T[pix * 66 + oc] = (short)f2bf(v);
        }
    }
    __syncthreads();

    // ---- phase 4: im2col pairs -> h2colT[p2][k2=tap*64+c] (stride 584)
    for (int i = t; i < 4608; i += 256) {
        const int p2 = i & 15, kp = i >> 4;         // kp = tap*32 + c2
        const int c2 = kp & 31, tap = kp >> 5;
        const int ky = (tap * 11) >> 5, kx = tap - 3 * ky;
        const int y2 = p2 >> 2, x2 = p2 & 3;
        const int pix = (2 * y2 + ky) * 10 + (2 * x2 + kx);
        const unsigned v = *(const unsigned*)&H1T[pix * 66 + 2 * c2];
        *(unsigned*)&H2C[p2 * 584 + tap * 64 + 2 * c2] = v;
    }
    __syncthreads();

    // ---- phase 5: conv2 MFMA. wave: mi = w&1 (oc tile), kh = w>>1 (K half)
    {
        const int mi = w & 1, kh = w >> 1;
        f4v c2 = (f4v){0.f, 0.f, 0.f, 0.f};
        const short* wrow = w2b + (mi * 16 + lm) * 584 + kh * 288 + lq * 8;
        const short* hrow = H2C + lm * 584 + kh * 288 + lq * 8;
        #pragma unroll
        for (int ks = 0; ks < 9; ++ks) {
            s8v a  = *(const s8v*)(wrow + ks * 32);
            s8v bb = *(const s8v*)(hrow + ks * 32);
            c2 = MFMA(a, bb, c2);
        }
        if (kh == 1) *(f4v*)&SCR[(mi * 64 + l) * 4] = c2;
        __syncthreads();
        if (kh == 0) {
            f4v oth = *(const f4v*)&SCR[(mi * 64 + l) * 4];
            #pragma unroll
            for (int r = 0; r < 4; ++r) {
                const int oc = mi * 16 + lq * 4 + r;
                float v = c2[r] + oth[r];
                h2pre[(size_t)b * 512 + oc * 16 + lm] = v;
                float s1 = v, s2 = v * v;
                #pragma unroll
                for (int m = 1; m < 16; m <<= 1) {
                    s1 += __shfl_xor(s1, m, 16);
                    s2 += __shfl_xor(s2, m, 16);
                }
                if (lm == 0) { CS[oc] = s1; CS2[oc] = s2; }
            }
        }
    }
    __syncthreads();
    if (t < 32) {
        atomicAdd(&bn2s[t],  CS[t]);
        atomicAdd(&bn2s2[t], CS2[t]);
    }
}

// ---------------------------------------------------------------------------
// stage2: 4 b per block. BN2+lrelu, conv3, BN3 sums
// ---------------------------------------------------------------------------
__global__ __launch_bounds__(256) void stage2(
    const float* __restrict__ h2pre,
    const float* __restrict__ gamma2, const float* __restrict__ beta2,
    const float* __restrict__ w3,
    const float* __restrict__ bn2s, const float* __restrict__ bn2s2,
    float* __restrict__ h3pre,
    float* __restrict__ bn3s, float* __restrict__ bn3s2, int B)
{
    const int b0 = blockIdx.x * 4, t = threadIdx.x;
    __shared__ float s_scale[32], s_shift[32];
    __shared__ float s_pad[4 * 32 * 36];
    __shared__ float s_c3[16], s_c32[16];

    if (t < 32) {
        const float n = (float)B * 16.f;
        const float mean = bn2s[t] / n;
        const float var  = bn2s2[t] / n - mean * mean;
        const float sc   = gamma2[t] * rsqrtf(var + BN_EPS);
        s_scale[t] = sc;
        s_shift[t] = beta2[t] - mean * sc;
    }
    if (t < 16) { s_c3[t] = 0.f; s_c32[t] = 0.f; }
    for (int i = t; i < 4 * 32 * 36; i += 256) s_pad[i] = 0.f;
    __syncthreads();

    for (int i = t; i < 2048; i += 256) {
        const int lb = i >> 9, r = i & 511;
        const int c = r >> 4, p = r & 15, y = p >> 2, x = p & 3;
        const float v = h2pre[(size_t)b0 * 512 + i] * s_scale[c] + s_shift[c];
        const float a = (v >= 0.f) ? v : SLOPE * v;
        s_pad[lb * 1152 + c * 36 + (y + 1) * 6 + (x + 1)] = a;
    }
    __syncthreads();

    {
        const int lb = t >> 6, r = t & 63;
        const int oc = r >> 2, p = r & 3, y = p >> 1, x = p & 1;
        float acc = 0.f;
        const float* wp = w3 + oc * 288;
        const float* hp = &s_pad[lb * 1152];
        for (int c = 0; c < 32; ++c) {
            const float* hc = hp + c * 36;
            #pragma unroll
            for (int ky = 0; ky < 3; ++ky)
                #pragma unroll
                for (int kx = 0; kx < 3; ++kx)
                    acc += wp[c * 9 + ky * 3 + kx] * hc[(2 * y + ky) * 6 + (2 * x + kx)];
        }
        h3pre[(size_t)b0 * 64 + t] = acc;
        atomicAdd(&s_c3[oc],  acc);
        atomicAdd(&s_c32[oc], acc * acc);
    }
    __syncthreads();
    if (t < 16) {
        atomicAdd(&bn3s[t],  s_c3[t]);
        atomicAdd(&bn3s2[t], s_c32[t]);
    }
}

// ---------------------------------------------------------------------------
// stage3: BN3 + lrelu -> out
// ---------------------------------------------------------------------------
__global__ __launch_bounds__(256) void stage3(
    const float* __restrict__ h3pre,
    const float* __restrict__ gamma3, const float* __restrict__ beta3,
    const float* __restrict__ bn3s, const float* __restrict__ bn3s2,
    float* __restrict__ out, int total, int B)
{
    __shared__ float s_scale[16], s_shift[16];
    if (threadIdx.x < 16) {
        const int c = threadIdx.x;
        const float n = (float)B * 4.f;
        const float mean = bn3s[c] / n;
        const float var  = bn3s2[c] / n - mean * mean;
        const float sc   = gamma3[c] * rsqrtf(var + BN_EPS);
        s_scale[c] = sc;
        s_shift[c] = beta3[c] - mean * sc;
    }
    __syncthreads();
    const int idx = blockIdx.x * 256 + threadIdx.x;
    if (idx < total) {
        const int c = (idx & 63) >> 2;
        const float v = h3pre[idx] * s_scale[c] + s_shift[c];
        out[idx] = (v >= 0.f) ? v : SLOPE * v;
    }
}

extern "C" void kernel_launch(void* const* d_in, const int* in_sizes, int n_in,
                              void* d_out, int out_size, void* d_ws, size_t ws_size,
                              hipStream_t stream)
{
    const float* labels = (const float*)d_in[0];
    const float* theta  = (const float*)d_in[1];
    const float* w1     = (const float*)d_in[2];
    const float* w2     = (const float*)d_in[3];
    const float* gamma2 = (const float*)d_in[4];
    const float* beta2  = (const float*)d_in[5];
    const float* w3     = (const float*)d_in[6];
    const float* gamma3 = (const float*)d_in[7];
    const float* beta3  = (const float*)d_in[8];
    const int*   maxobj = (const int*)d_in[9];

    const int B = in_sizes[0] / (O_MAX * C_DIM);   // 2048

    unsigned char* ws = (unsigned char*)d_ws;
    float* h2pre = (float*)ws;                                  // B*512 f32
    float* h3pre = h2pre + (size_t)B * 512;                     // B*64
    float* sums  = h3pre + (size_t)B * 64;                      // 96
    short* w1n   = (short*)(sums + 96);                         // 73728 sh
    short* w2b   = w1n + N_W1N;                                 // 18688 sh
    float* bn2s  = sums;
    float* bn2s2 = sums + 32;
    float* bn3s  = sums + 64;
    float* bn3s2 = sums + 80;

    const int prep_total = N_W1N + N_W2B + 96;
    prep<<<(prep_total + 255) / 256, 256, 0, stream>>>(w1, w2, w1n, w2b, sums);
    stage1<<<B, 256, 0, stream>>>(labels, theta, w1n, w2b, maxobj,
                                  h2pre, bn2s, bn2s2);
    stage2<<<B / 4, 256, 0, stream>>>(h2pre, gamma2, beta2, w3, bn2s, bn2s2,
                                      h3pre, bn3s, bn3s2, B);
    const int total = B * 64;
    stage3<<<(total + 255) / 256, 256, 0, stream>>>(h3pre, gamma3, beta3,
                                                    bn3s, bn3s2, (float*)d_out,
                                                    total, B);
}